// Round 18
// baseline (217.903 us; speedup 1.0000x reference)
//
#include <hip/hip_runtime.h>
#include <math.h>

#define S_LEN 2048
#define DIM   1024
#define HEADS 16
#define DK    64
#define BATCH 4

typedef __bf16 bf16;
typedef bf16  bf16x8 __attribute__((ext_vector_type(8)));
typedef bf16  bf16x4 __attribute__((ext_vector_type(4)));
typedef float f32x4  __attribute__((ext_vector_type(4)));
typedef unsigned long long u64;

#define QSCALE (0.125f * 1.44269504088896f)   // 1/sqrt(dk) * log2(e)

__device__ __forceinline__ void gload16(const void* g, void* l) {
  __builtin_amdgcn_global_load_lds((const __attribute__((address_space(1))) void*)g,
                                   (__attribute__((address_space(3))) void*)l, 16, 0, 0);
}
__device__ __forceinline__ float exp2fast(float x) {
  float r; asm("v_exp_f32 %0, %1" : "=v"(r) : "v"(x)); return r;
}
__device__ __forceinline__ unsigned cvt_pk_bf16(float a, float b) {
  unsigned r; asm("v_cvt_pk_bf16_f32 %0, %1, %2" : "=v"(r) : "v"(a), "v"(b)); return r;
}

// ---------------------------------------------------------------------------
// Combined BW-bound pass: f32->bf16 conversion of all 7 tensors + mask
// bitpack, one dispatch (all short streaming blocks). (unchanged)
// ---------------------------------------------------------------------------
__global__ __launch_bounds__(256)
void conv_pack(const float* __restrict__ q, const float* __restrict__ k,
               const float* __restrict__ v,
               const float* __restrict__ Wq, const float* __restrict__ Wk,
               const float* __restrict__ Wv, const float* __restrict__ Wo,
               bf16* __restrict__ qB, bf16* __restrict__ kB, bf16* __restrict__ vB,
               bf16* __restrict__ WqB, bf16* __restrict__ WkB,
               bf16* __restrict__ WvB, bf16* __restrict__ WoB,
               const int* __restrict__ mask, u64* __restrict__ bits)
{
  const int y = blockIdx.y;
  if (y == 4) {
    const int lane = threadIdx.x & 63;
    const size_t w0 = (size_t)blockIdx.x * 64 + (threadIdx.x >> 6);
    #pragma unroll
    for (int it = 0; it < 16; ++it) {
      const size_t w = w0 + it * 4;
      const u64 bb = __ballot(mask[w * 64 + lane] != 0);
      if (lane == 0) bits[w] = bb;
    }
    return;
  }
  const float* in;
  bf16* out;
  size_t idx;
  if (y < 3) {
    in  = (y == 0) ? q  : (y == 1) ? k  : v;
    out = (y == 0) ? qB : (y == 1) ? kB : vB;
    idx = ((size_t)blockIdx.x * 256 + threadIdx.x) * 8;
  } else {
    if (blockIdx.x >= 2048) return;
    const int wsel = blockIdx.x >> 9, inner = blockIdx.x & 511;
    in  = (wsel == 0) ? Wq  : (wsel == 1) ? Wk  : (wsel == 2) ? Wv  : Wo;
    out = (wsel == 0) ? WqB : (wsel == 1) ? WkB : (wsel == 2) ? WvB : WoB;
    idx = ((size_t)inner * 256 + threadIdx.x) * 8;
  }
  float4 a = *reinterpret_cast<const float4*>(&in[idx]);
  float4 b = *reinterpret_cast<const float4*>(&in[idx + 4]);
  bf16x8 r;
  r[0] = (bf16)a.x; r[1] = (bf16)a.y; r[2] = (bf16)a.z; r[3] = (bf16)a.w;
  r[4] = (bf16)b.x; r[5] = (bf16)b.y; r[6] = (bf16)b.z; r[7] = (bf16)b.w;
  *reinterpret_cast<bf16x8*>(&out[idx]) = r;
}

// ---------------------------------------------------------------------------
// Merged QKV GEMMs (unchanged round-17 structure): BK=32, 3 LDS buffers,
// stage depth 2, counted vmcnt (never 0 in steady loop).
// ---------------------------------------------------------------------------
__global__ __launch_bounds__(256, 3)
void gemm_qkv(const bf16* __restrict__ qB, const bf16* __restrict__ kB,
              const bf16* __restrict__ vB,
              const bf16* __restrict__ WqB, const bf16* __restrict__ WkB,
              const bf16* __restrict__ WvB,
              const float* __restrict__ bq, const float* __restrict__ bk,
              const float* __restrict__ bv,
              bf16* __restrict__ Qb, bf16* __restrict__ Kb,
              bf16* __restrict__ Vt)
{
  __shared__ __align__(16) bf16 AB[3][128][64];   // 48 KB
  const int tid = threadIdx.x;
  const int which = blockIdx.x >> 9;
  const int inner = blockIdx.x & 511;
  const bf16* A     = (which == 0) ? qB  : (which == 1) ? kB  : vB;
  const bf16* W     = (which == 0) ? WqB : (which == 1) ? WkB : WvB;
  const float* bias = (which == 0) ? bq  : (which == 1) ? bk  : bv;

  const int lane = tid & 63, wid = tid >> 6;
  const int l15  = lane & 15, lg = lane >> 4;
  const int L  = (inner & 7) * 64 + (inner >> 3);
  const int m0 = (L >> 3) * 128, n0 = (L & 7) * 128;
  const int wm = wid >> 1, wn = wid & 1;

  const char* src0; const char* src1; const char* src2; const char* src3;
  char* dst0; char* dst1; char* dst2; char* dst3;
  {
    #define MKCH(J, SRC, DST)                                                  \
      { const int c = (J) * 256 + tid;                                         \
        const int r = c >> 3;                                                  \
        const int g = (c & 7) ^ (r & 7);                                       \
        SRC = ((g < 4) ? (const char*)A + (size_t)(m0 + r) * 2048              \
                       : (const char*)W + (size_t)(n0 + r) * 2048) + (g & 3) * 16; \
        DST = (char*)&AB[0][0][0] + c * 16; }
    MKCH(0, src0, dst0) MKCH(1, src1, dst1) MKCH(2, src2, dst2) MKCH(3, src3, dst3)
    #undef MKCH
  }

  gload16(src0, dst0); gload16(src1, dst1); gload16(src2, dst2); gload16(src3, dst3);
  src0 += 64; src1 += 64; src2 += 64; src3 += 64;
  gload16(src0, dst0 + 16384); gload16(src1, dst1 + 16384);
  gload16(src2, dst2 + 16384); gload16(src3, dst3 + 16384);
  src0 += 64; src1 += 64; src2 += 64; src3 += 64;

  const unsigned swz  = (l15 & 7) << 4;
  const unsigned aoff = (unsigned)(wm * 64 + l15) * 128 + ((lg * 16) ^ swz);
  const unsigned boff = (unsigned)(wn * 64 + l15) * 128 + ((64 + lg * 16) ^ swz);
  const char* ABB = (const char*)&AB[0][0][0];

  unsigned tb = 0;
  unsigned sb = 2u * 16384;

  f32x4 acc[4][4] = {};

  for (int t = 0; t < 32; ++t) {
    if (t < 30) {
      gload16(src0, dst0 + sb); gload16(src1, dst1 + sb);
      gload16(src2, dst2 + sb); gload16(src3, dst3 + sb);
      src0 += 64; src1 += 64; src2 += 64; src3 += 64;
      asm volatile("s_waitcnt vmcnt(8)" ::: "memory");
    } else if (t == 30) {
      asm volatile("s_waitcnt vmcnt(4)" ::: "memory");
    } else {
      asm volatile("s_waitcnt vmcnt(0)" ::: "memory");
    }
    __builtin_amdgcn_s_barrier();
    asm volatile("" ::: "memory");

    bf16x8 af[4], bfr[4];
    #pragma unroll
    for (int i = 0; i < 4; ++i) {
      af[i]  = *reinterpret_cast<const bf16x8*>(ABB + tb + aoff + i * 2048);
      bfr[i] = *reinterpret_cast<const bf16x8*>(ABB + tb + boff + i * 2048);
    }
    __builtin_amdgcn_s_setprio(1);
    #pragma unroll
    for (int mi = 0; mi < 4; ++mi)
      #pragma unroll
      for (int ni = 0; ni < 4; ++ni)
        acc[mi][ni] = __builtin_amdgcn_mfma_f32_16x16x32_bf16(af[mi], bfr[ni], acc[mi][ni], 0, 0, 0);
    __builtin_amdgcn_s_setprio(0);

    asm volatile("" ::: "memory");
    __builtin_amdgcn_s_barrier();
    asm volatile("" ::: "memory");

    tb = (tb == 2u * 16384) ? 0u : tb + 16384;
    sb = (sb == 2u * 16384) ? 0u : sb + 16384;
  }

  #pragma unroll
  for (int ni = 0; ni < 4; ++ni) {
    const int col = n0 + wn * 64 + ni * 16 + l15;
    const float bi = bias[col];
    #pragma unroll
    for (int mi = 0; mi < 4; ++mi) {
      const int row0 = m0 + wm * 64 + mi * 16 + lg * 4;
      if (which == 0) {
        #pragma unroll
        for (int r = 0; r < 4; ++r)
          Qb[(size_t)(row0 + r) * DIM + col] = (bf16)((acc[mi][ni][r] + bi) * QSCALE);
      } else if (which == 1) {
        #pragma unroll
        for (int r = 0; r < 4; ++r)
          Kb[(size_t)(row0 + r) * DIM + col] = (bf16)(acc[mi][ni][r] + bi);
      } else {
        bf16x4 vv;
        #pragma unroll
        for (int r = 0; r < 4; ++r) vv[r] = (bf16)(acc[mi][ni][r] + bi);
        const int seq = row0 & (S_LEN - 1);
        const int t6  = seq & 63;
        const int p0  = (seq & ~63) + ((t6 >> 5) << 5) + (((t6 >> 2) & 3) << 3)
                      + (((t6 >> 4) & 1) << 2);
        *reinterpret_cast<bf16x4*>(
            &Vt[((size_t)(row0 >> 11) * DIM + col) * S_LEN + p0]) = vv;
      }
    }
  }
}

// ---------------------------------------------------------------------------
// O-projection GEMM (unchanged round-17 structure).
// ---------------------------------------------------------------------------
__global__ __launch_bounds__(256, 3)
void gemm_out(const bf16* __restrict__ A, const bf16* __restrict__ W,
              const float* __restrict__ bias, float* __restrict__ out)
{
  __shared__ __align__(16) bf16 AB[3][128][64];
  const int tid  = threadIdx.x;
  const int lane = tid & 63, wid = tid >> 6;
  const int l15  = lane & 15, lg = lane >> 4;
  const int L  = (blockIdx.x & 7) * 64 + (blockIdx.x >> 3);
  const int m0 = (L >> 3) * 128, n0 = (L & 7) * 128;
  const int wm = wid >> 1, wn = wid & 1;

  const char* src0; const char* src1; const char* src2; const char* src3;
  char* dst0; char* dst1; char* dst2; char* dst3;
  {
    #define MKCH(J, SRC, DST)                                                  \
      { const int c = (J) * 256 + tid;                                         \
        const int r = c >> 3;                                                  \
        const int g = (c & 7) ^ (r & 7);                                       \
        SRC = ((g < 4) ? (const char*)A + (size_t)(m0 + r) * 2048              \
                       : (const char*)W + (size_t)(n0 + r) * 2048) + (g & 3) * 16; \
        DST = (char*)&AB[0][0][0] + c * 16; }
    MKCH(0, src0, dst0) MKCH(1, src1, dst1) MKCH(2, src2, dst2) MKCH(3, src3, dst3)
    #undef MKCH
  }

  gload16(src0, dst0); gload16(src1, dst1); gload16(src2, dst2); gload16(src3, dst3);
  src0 += 64; src1 += 64; src2 += 64; src3 += 64;
  gload16(src0, dst0 + 16384); gload16(src1, dst1 + 16384);
  gload16(src2, dst2 + 16384); gload16(src3, dst3 + 16384);
  src0 += 64; src1 += 64; src2 += 64; src3 += 64;

  const unsigned swz  = (l15 & 7) << 4;
  const unsigned aoff = (unsigned)(wm * 64 + l15) * 128 + ((lg * 16) ^ swz);
  const unsigned boff = (unsigned)(wn * 64 + l15) * 128 + ((64 + lg * 16) ^ swz);
  const char* ABB = (const char*)&AB[0][0][0];

  unsigned tb = 0;
  unsigned sb = 2u * 16384;

  f32x4 acc[4][4] = {};

  for (int t = 0; t < 32; ++t) {
    if (t < 30) {
      gload16(src0, dst0 + sb); gload16(src1, dst1 + sb);
      gload16(src2, dst2 + sb); gload16(src3, dst3 + sb);
      src0 += 64; src1 += 64; src2 += 64; src3 += 64;
      asm volatile("s_waitcnt vmcnt(8)" ::: "memory");
    } else if (t == 30) {
      asm volatile("s_waitcnt vmcnt(4)" ::: "memory");
    } else {
      asm volatile("s_waitcnt vmcnt(0)" ::: "memory");
    }
    __builtin_amdgcn_s_barrier();
    asm volatile("" ::: "memory");

    bf16x8 af[4], bfr[4];
    #pragma unroll
    for (int i = 0; i < 4; ++i) {
      af[i]  = *reinterpret_cast<const bf16x8*>(ABB + tb + aoff + i * 2048);
      bfr[i] = *reinterpret_cast<const bf16x8*>(ABB + tb + boff + i * 2048);
    }
    __builtin_amdgcn_s_setprio(1);
    #pragma unroll
    for (int mi = 0; mi < 4; ++mi)
      #pragma unroll
      for (int ni = 0; ni < 4; ++ni)
        acc[mi][ni] = __builtin_amdgcn_mfma_f32_16x16x32_bf16(af[mi], bfr[ni], acc[mi][ni], 0, 0, 0);
    __builtin_amdgcn_s_setprio(0);

    asm volatile("" ::: "memory");
    __builtin_amdgcn_s_barrier();
    asm volatile("" ::: "memory");

    tb = (tb == 2u * 16384) ? 0u : tb + 16384;
    sb = (sb == 2u * 16384) ? 0u : sb + 16384;
  }

  #pragma unroll
  for (int ni = 0; ni < 4; ++ni) {
    const int col = n0 + wn * 64 + ni * 16 + l15;
    const float bi = bias[col];
    #pragma unroll
    for (int mi = 0; mi < 4; ++mi) {
      const int row0 = m0 + wm * 64 + mi * 16 + lg * 4;
      #pragma unroll
      for (int r = 0; r < 4; ++r)
        out[(size_t)(row0 + r) * DIM + col] = acc[mi][ni][r] + bi;
    }
  }
}

// ---------------------------------------------------------------------------
// Flash attention, qg=4: block = 4 waves x 64 q-rows (block owns 256 q),
// grid 512 (same XCD decode). kf/vf LDS reads are qg-invariant -> per-unit-
// work DS reads HALVE vs qg=2; 4 independent QK->SM->PV chains per wave give
// the scheduler ILP to cover the 2-waves/SIMD occupancy. Each thread stages
// 2 chunks of K + 2 of V per tile. Everything else = round-16 attn.
// ---------------------------------------------------------------------------
__global__ __launch_bounds__(256, 2)
void attn_fwd(const bf16* __restrict__ Qb, const bf16* __restrict__ Kb,
              const bf16* __restrict__ Vt, const u64* __restrict__ mbits,
              bf16* __restrict__ ctx)
{
  __shared__ __align__(16) bf16 Kbuf[2][64][64];
  __shared__ __align__(16) bf16 Vbuf[2][64][64];
  __shared__ u64 lutm[16];

  const int tid  = threadIdx.x;          // 0..255
  const int lane = tid & 63;
  const int l15  = lane & 15, lg = lane >> 4;
  const int L  = (blockIdx.x & 7) * 64 + (blockIdx.x >> 3);
  const int qi = L & 7;
  const int hb = L >> 3;
  const int h  = hb & 15, b = hb >> 4;
  const int w  = tid >> 6;               // 0..3
  const int qbase = qi * 256 + w * 64;   // wave owns 64 q-rows

  if (tid < 16) {
    lutm[tid] = ((tid & 1) ? 0xFFFFull : 0) | ((tid & 2) ? 0xFFFF0000ull : 0)
              | ((tid & 4) ? 0xFFFF00000000ull : 0)
              | ((tid & 8) ? 0xFFFF000000000000ull : 0);
  }

  // staging: chunks c0 = tid (rows 0..31), c1 = tid+256 (rows 32..63)
  const int rr0 = tid >> 3, rr1 = rr0 + 32;
  const int cG0 = ((tid & 7) << 4) ^ ((rr0 & 7) << 4);
  const char* gk0 = (const char*)Kb + ((size_t)(b * S_LEN + rr0) * DIM + h * DK) * 2 + cG0;
  const char* gk1 = (const char*)Kb + ((size_t)(b * S_LEN + rr1) * DIM + h * DK) * 2 + cG0;
  const char* gv0 = (const char*)Vt + ((size_t)b * DIM + h * DK + rr0) * (S_LEN * 2) + cG0;
  const char* gv1 = (const char*)Vt + ((size_t)b * DIM + h * DK + rr1) * (S_LEN * 2) + cG0;
  char* lK0 = (char*)&Kbuf[0][0][0] + tid * 16;
  char* lV0 = (char*)&Vbuf[0][0][0] + tid * 16;

  const unsigned xo  = (l15 & 7) << 4;
  const unsigned ko0 = l15 * 128 + ((lg * 16) ^ xo);
  const unsigned ko1 = l15 * 128 + (((64 + lg * 16)) ^ xo);
  const char* KB = (const char*)&Kbuf[0][0][0];
  const char* VB = (const char*)&Vbuf[0][0][0];

  // Q fragments (B-operand), rows q = qbase + qg*16 + l15  (Q prescaled)
  bf16x8 qf[4][2];
  #pragma unroll
  for (int qg = 0; qg < 4; ++qg) {
    const size_t qrow = (size_t)b * S_LEN + qbase + qg * 16 + l15;
    #pragma unroll
    for (int s = 0; s < 2; ++s)
      qf[qg][s] = *reinterpret_cast<const bf16x8*>(&Qb[qrow * DIM + h * DK + s * 32 + lg * 8]);
  }

  bf16x8 onesf;
  #pragma unroll
  for (int j = 0; j < 8; ++j) onesf[j] = (bf16)1.0f;

  union pqu { unsigned u[8]; bf16x8 frag[2]; };

  f32x4 o[4][4] = {};
  f32x4 o_l[4] = {};
  // mask rows: qg stride = 16 rows * 32 words = 512
  const u64* mp = mbits + ((size_t)b * S_LEN + qbase + l15) * (S_LEN / 64);

  gload16(gk0, lK0); gload16(gk1, lK0 + 4096);
  gload16(gv0, lV0); gload16(gv1, lV0 + 4096);
  gk0 += 64 * DIM * 2; gk1 += 64 * DIM * 2;
  gv0 += 64 * 2;       gv1 += 64 * 2;
  u64 mbc[4] = { mp[0], mp[512], mp[1024], mp[1536] };
  mp++;

  const int NT = S_LEN / 64;   // 32
  for (int t = 0; t < NT; ++t) {
    asm volatile("s_waitcnt vmcnt(0)" ::: "memory");
    __syncthreads();

    u64 mbn[4] = {0, 0, 0, 0};
    if (t + 1 < NT) {
      mbn[0] = mp[0]; mbn[1] = mp[512]; mbn[2] = mp[1024]; mbn[3] = mp[1536];
      mp++;
      const unsigned nb = ((t + 1) & 1) << 13;
      gload16(gk0, lK0 + nb); gload16(gk1, lK0 + nb + 4096);
      gload16(gv0, lV0 + nb); gload16(gv1, lV0 + nb + 4096);
      gk0 += 64 * DIM * 2; gk1 += 64 * DIM * 2;
      gv0 += 64 * 2;       gv1 += 64 * 2;
    }

    const unsigned tb = (t & 1) << 13;

    // --- QK^T: sc[qg][nf][r], kf shared across all 4 qg
    f32x4 sc[4][4] = {};
    __builtin_amdgcn_s_setprio(1);
    #pragma unroll
    for (int s = 0; s < 2; ++s) {
      const char* kp = KB + tb + (s ? ko1 : ko0);
      #pragma unroll
      for (int nf = 0; nf < 4; ++nf) {
        bf16x8 kf = *reinterpret_cast<const bf16x8*>(kp + nf * 2048);
        #pragma unroll
        for (int qg = 0; qg < 4; ++qg)
          sc[qg][nf] = __builtin_amdgcn_mfma_f32_16x16x32_bf16(kf, qf[qg][s], sc[qg][nf], 0, 0, 0);
      }
    }
    __builtin_amdgcn_s_setprio(0);

    // --- softmax: p = exp2(sc); mask via LDS LUT
    pqu W[4];
    #pragma unroll
    for (int qg = 0; qg < 4; ++qg) {
      const u64 sh = mbc[qg] >> (lg * 4);
      #pragma unroll
      for (int nf = 0; nf < 4; ++nf) {
        const unsigned idx = ((unsigned)(sh >> (nf * 16))) & 15u;
        const u64 mk = lutm[idx];
        float e0 = exp2fast(sc[qg][nf][0]);
        float e1 = exp2fast(sc[qg][nf][1]);
        float e2 = exp2fast(sc[qg][nf][2]);
        float e3 = exp2fast(sc[qg][nf][3]);
        W[qg].u[nf * 2 + 0] = cvt_pk_bf16(e0, e1) & (unsigned)mk;
        W[qg].u[nf * 2 + 1] = cvt_pk_bf16(e2, e3) & (unsigned)(mk >> 32);
      }
    }

    // --- PV: vf shared across all 4 qg
    __builtin_amdgcn_s_setprio(1);
    #pragma unroll
    for (int s = 0; s < 2; ++s) {
      const char* vp = VB + tb + (s ? ko1 : ko0);
      #pragma unroll
      for (int nf = 0; nf < 4; ++nf) {
        bf16x8 vf = *reinterpret_cast<const bf16x8*>(vp + nf * 2048);
        #pragma unroll
        for (int qg = 0; qg < 4; ++qg)
          o[qg][nf] = __builtin_amdgcn_mfma_f32_16x16x32_bf16(W[qg].frag[s], vf, o[qg][nf], 0, 0, 0);
      }
      #pragma unroll
      for (int qg = 0; qg < 4; ++qg)
        o_l[qg] = __builtin_amdgcn_mfma_f32_16x16x32_bf16(W[qg].frag[s], onesf, o_l[qg], 0, 0, 0);
    }
    __builtin_amdgcn_s_setprio(0);

    mbc[0] = mbn[0]; mbc[1] = mbn[1]; mbc[2] = mbn[2]; mbc[3] = mbn[3];
  }

  // --- epilogue
  #pragma unroll
  for (int qg = 0; qg < 4; ++qg) {
    float lf[4];
    #pragma unroll
    for (int r = 0; r < 4; ++r) lf[r] = 1.0f / o_l[qg][r];
    #pragma unroll
    for (int nf = 0; nf < 4; ++nf)
      #pragma unroll
      for (int r = 0; r < 4; ++r) {
        const int q = qbase + qg * 16 + lg * 4 + r;
        ctx[((size_t)b * S_LEN + q) * DIM + h * DK + nf * 16 + l15] = (bf16)(o[qg][nf][r] * lf[r]);
      }
  }
}

// ---------------------------------------------------------------------------
extern "C" void kernel_launch(void* const* d_in, const int* in_sizes, int n_in,
                              void* d_out, int out_size, void* d_ws, size_t ws_size,
                              hipStream_t stream)
{
  const float* q    = (const float*)d_in[0];
  const float* k    = (const float*)d_in[1];
  const float* v    = (const float*)d_in[2];
  const int*   mask = (const int*)  d_in[3];
  const float* Wq   = (const float*)d_in[4];
  const float* bq   = (const float*)d_in[5];
  const float* Wk   = (const float*)d_in[6];
  const float* bk   = (const float*)d_in[7];
  const float* Wv   = (const float*)d_in[8];
  const float* bv   = (const float*)d_in[9];
  const float* Wo   = (const float*)d_in[10];
  const float* bo   = (const float*)d_in[11];
  float* out = (float*)d_out;

  const size_t NE = (size_t)BATCH * S_LEN * DIM;  // 8.39M elements
  const size_t NW = (size_t)DIM * DIM;            // 1.05M elements
  bf16* qB  = (bf16*)d_ws;                        // bf16 copies of inputs
  bf16* kB  = qB + NE;
  bf16* vB  = kB + NE;
  bf16* Qb  = vB + NE;                            // projected Q,K,V
  bf16* Kb  = Qb + NE;
  bf16* Vt  = Kb + NE;
  bf16* WqB = Vt + NE;                            // bf16 weights
  bf16* WkB = WqB + NW;
  bf16* WvB = WkB + NW;
  bf16* WoB = WvB + NW;
  u64*  bits = (u64*)(WoB + NW);                  // 2 MB
  bf16* ctx = qB;                                 // reuse: qB dead after QKV GEMMs

  conv_pack<<<dim3(4096, 5), 256, 0, stream>>>(q, k, v, Wq, Wk, Wv, Wo,
                                               qB, kB, vB, WqB, WkB, WvB, WoB,
                                               mask, bits);

  gemm_qkv<<<1536, 256, 0, stream>>>(qB, kB, vB, WqB, WkB, WvB,
                                     bq, bk, bv, Qb, Kb, Vt);

  attn_fwd<<<512, 256, 0, stream>>>(Qb, Kb, Vt, bits, ctx);

  gemm_out<<<512, 256, 0, stream>>>(ctx, WoB, bo, out);
}

// Round 19
// 213.688 us; speedup vs baseline: 1.0197x; 1.0197x over previous
//
#include <hip/hip_runtime.h>
#include <math.h>

#define S_LEN 2048
#define DIM   1024
#define HEADS 16
#define DK    64
#define BATCH 4

typedef __bf16 bf16;
typedef bf16  bf16x8 __attribute__((ext_vector_type(8)));
typedef bf16  bf16x4 __attribute__((ext_vector_type(4)));
typedef float f32x4  __attribute__((ext_vector_type(4)));
typedef unsigned long long u64;

#define QSCALE (0.125f * 1.44269504088896f)   // 1/sqrt(dk) * log2(e)

__device__ __forceinline__ void gload16(const void* g, void* l) {
  __builtin_amdgcn_global_load_lds((const __attribute__((address_space(1))) void*)g,
                                   (__attribute__((address_space(3))) void*)l, 16, 0, 0);
}
__device__ __forceinline__ float exp2fast(float x) {
  float r; asm("v_exp_f32 %0, %1" : "=v"(r) : "v"(x)); return r;
}
__device__ __forceinline__ unsigned cvt_pk_bf16(float a, float b) {
  unsigned r; asm("v_cvt_pk_bf16_f32 %0, %1, %2" : "=v"(r) : "v"(a), "v"(b)); return r;
}

// ---------------------------------------------------------------------------
// Combined BW-bound pass (unchanged).
// ---------------------------------------------------------------------------
__global__ __launch_bounds__(256)
void conv_pack(const float* __restrict__ q, const float* __restrict__ k,
               const float* __restrict__ v,
               const float* __restrict__ Wq, const float* __restrict__ Wk,
               const float* __restrict__ Wv, const float* __restrict__ Wo,
               bf16* __restrict__ qB, bf16* __restrict__ kB, bf16* __restrict__ vB,
               bf16* __restrict__ WqB, bf16* __restrict__ WkB,
               bf16* __restrict__ WvB, bf16* __restrict__ WoB,
               const int* __restrict__ mask, u64* __restrict__ bits)
{
  const int y = blockIdx.y;
  if (y == 4) {
    const int lane = threadIdx.x & 63;
    const size_t w0 = (size_t)blockIdx.x * 64 + (threadIdx.x >> 6);
    #pragma unroll
    for (int it = 0; it < 16; ++it) {
      const size_t w = w0 + it * 4;
      const u64 bb = __ballot(mask[w * 64 + lane] != 0);
      if (lane == 0) bits[w] = bb;
    }
    return;
  }
  const float* in;
  bf16* out;
  size_t idx;
  if (y < 3) {
    in  = (y == 0) ? q  : (y == 1) ? k  : v;
    out = (y == 0) ? qB : (y == 1) ? kB : vB;
    idx = ((size_t)blockIdx.x * 256 + threadIdx.x) * 8;
  } else {
    if (blockIdx.x >= 2048) return;
    const int wsel = blockIdx.x >> 9, inner = blockIdx.x & 511;
    in  = (wsel == 0) ? Wq  : (wsel == 1) ? Wk  : (wsel == 2) ? Wv  : Wo;
    out = (wsel == 0) ? WqB : (wsel == 1) ? WkB : (wsel == 2) ? WvB : WoB;
    idx = ((size_t)inner * 256 + threadIdx.x) * 8;
  }
  float4 a = *reinterpret_cast<const float4*>(&in[idx]);
  float4 b = *reinterpret_cast<const float4*>(&in[idx + 4]);
  bf16x8 r;
  r[0] = (bf16)a.x; r[1] = (bf16)a.y; r[2] = (bf16)a.z; r[3] = (bf16)a.w;
  r[4] = (bf16)b.x; r[5] = (bf16)b.y; r[6] = (bf16)b.z; r[7] = (bf16)b.w;
  *reinterpret_cast<bf16x8*>(&out[idx]) = r;
}

// ---------------------------------------------------------------------------
// GEMM v2: BM=256 (4 waves in M), BN=128, BK=32, wave frag = 4x8 (64x128).
// reads/MFMA = 12/32 = 0.375 (vs 0.5) -> +33% on the DS-bound model.
// 3 LDS buffers (24 KB each: A 256x64B + B 128x64B), depth-2 counted vmcnt.
// 64-B-row swizzle: cL ^= ((r>>1)&3)<<4 (2-way bank alias = free); read-side
// swizzle ((l15>>1)&3)<<4 is lane-constant -> fully hoisted.
// ---------------------------------------------------------------------------
#define G2_SETUP()                                                             \
  const int lane = tid & 63;                                                   \
  const int l15  = lane & 15, lg = lane >> 4;                                  \
  const int w    = tid >> 6;                                                   \
  const char* srcA0; const char* srcA1; const char* srcA2; const char* srcA3;  \
  const char* srcB0; const char* srcB1;                                        \
  char* dA0; char* dA1; char* dA2; char* dA3; char* dB0; char* dB1;            \
  {                                                                            \
    char* base = (char*)&AB[0];                                                \
    _Pragma("unroll")                                                          \
    for (int j = 0; j < 4; ++j) {                                              \
      const int c = j * 256 + tid;                                             \
      const int r = c >> 2;                                                    \
      const int cG = ((c & 3) << 4) ^ (((r >> 1) & 3) << 4);                   \
      const char* s = (const char*)A + (size_t)(m0 + r) * 2048 + cG;           \
      char* d = base + c * 16;                                                 \
      if (j == 0) { srcA0 = s; dA0 = d; } else if (j == 1) { srcA1 = s; dA1 = d; } \
      else if (j == 2) { srcA2 = s; dA2 = d; } else { srcA3 = s; dA3 = d; }    \
    }                                                                          \
    _Pragma("unroll")                                                          \
    for (int j = 0; j < 2; ++j) {                                              \
      const int c = j * 256 + tid;                                             \
      const int r = c >> 2;                                                    \
      const int cG = ((c & 3) << 4) ^ (((r >> 1) & 3) << 4);                   \
      const char* s = (const char*)W + (size_t)(n0 + r) * 2048 + cG;           \
      char* d = base + 16384 + c * 16;                                         \
      if (j == 0) { srcB0 = s; dB0 = d; } else { srcB1 = s; dB1 = d; }         \
    }                                                                          \
  }

#define G2_STAGE(SB) do {                                                      \
    gload16(srcA0, dA0 + (SB)); gload16(srcA1, dA1 + (SB));                    \
    gload16(srcA2, dA2 + (SB)); gload16(srcA3, dA3 + (SB));                    \
    gload16(srcB0, dB0 + (SB)); gload16(srcB1, dB1 + (SB));                    \
    srcA0 += 64; srcA1 += 64; srcA2 += 64; srcA3 += 64;                        \
    srcB0 += 64; srcB1 += 64;                                                  \
  } while (0)

#define G2_MAINLOOP()                                                          \
  G2_STAGE(0);                                                                 \
  G2_STAGE(24576);                                                             \
  const unsigned aswz = ((l15 >> 1) & 3) << 4;                                 \
  const unsigned aoff = (unsigned)(w * 64 + l15) * 64 + ((lg * 16) ^ aswz);    \
  const unsigned boff = 16384u + (unsigned)l15 * 64 + ((lg * 16) ^ aswz);      \
  const char* ABB = (const char*)&AB[0];                                       \
  unsigned tb = 0, sb = 2u * 24576;                                            \
  f32x4 acc[4][8] = {};                                                        \
  for (int t = 0; t < 32; ++t) {                                               \
    if (t < 30) {                                                              \
      G2_STAGE(sb);                                                            \
      asm volatile("s_waitcnt vmcnt(12)" ::: "memory");                        \
    } else if (t == 30) {                                                      \
      asm volatile("s_waitcnt vmcnt(6)" ::: "memory");                         \
    } else {                                                                   \
      asm volatile("s_waitcnt vmcnt(0)" ::: "memory");                         \
    }                                                                          \
    __builtin_amdgcn_s_barrier();                                              \
    asm volatile("" ::: "memory");                                             \
    bf16x8 af[4], bfr[8];                                                      \
    _Pragma("unroll")                                                          \
    for (int i = 0; i < 4; ++i)                                                \
      af[i]  = *reinterpret_cast<const bf16x8*>(ABB + tb + aoff + i * 1024);   \
    _Pragma("unroll")                                                          \
    for (int i = 0; i < 8; ++i)                                                \
      bfr[i] = *reinterpret_cast<const bf16x8*>(ABB + tb + boff + i * 1024);   \
    __builtin_amdgcn_s_setprio(1);                                             \
    _Pragma("unroll")                                                          \
    for (int mi = 0; mi < 4; ++mi)                                             \
      _Pragma("unroll")                                                        \
      for (int ni = 0; ni < 8; ++ni)                                           \
        acc[mi][ni] = __builtin_amdgcn_mfma_f32_16x16x32_bf16(af[mi], bfr[ni], acc[mi][ni], 0, 0, 0); \
    __builtin_amdgcn_s_setprio(0);                                             \
    asm volatile("" ::: "memory");                                             \
    __builtin_amdgcn_s_barrier();                                              \
    asm volatile("" ::: "memory");                                             \
    tb = (tb == 2u * 24576) ? 0u : tb + 24576;                                 \
    sb = (sb == 2u * 24576) ? 0u : sb + 24576;                                 \
  }

// Merged QKV: grid 768, which = bx>>8; inner 256 blocks XCD-chunked.
__global__ __launch_bounds__(256, 2)
void gemm_qkv(const bf16* __restrict__ qB, const bf16* __restrict__ kB,
              const bf16* __restrict__ vB,
              const bf16* __restrict__ WqB, const bf16* __restrict__ WkB,
              const bf16* __restrict__ WvB,
              const float* __restrict__ bq, const float* __restrict__ bk,
              const float* __restrict__ bv,
              bf16* __restrict__ Qb, bf16* __restrict__ Kb,
              bf16* __restrict__ Vt)
{
  __shared__ __align__(16) char AB[3 * 24576];   // 72 KB
  const int tid = threadIdx.x;
  const int which = blockIdx.x >> 8;
  const int inner = blockIdx.x & 255;
  const bf16* A     = (which == 0) ? qB  : (which == 1) ? kB  : vB;
  const bf16* W     = (which == 0) ? WqB : (which == 1) ? WkB : WvB;
  const float* bias = (which == 0) ? bq  : (which == 1) ? bk  : bv;

  const int L  = (inner & 7) * 32 + (inner >> 3);   // XCD-chunked
  const int m0 = (L >> 3) * 256, n0 = (L & 7) * 128;

  G2_SETUP();
  G2_MAINLOOP();

  #pragma unroll
  for (int ni = 0; ni < 8; ++ni) {
    const int col = n0 + ni * 16 + l15;
    const float bi = bias[col];
    #pragma unroll
    for (int mi = 0; mi < 4; ++mi) {
      const int row0 = m0 + w * 64 + mi * 16 + lg * 4;
      if (which == 0) {
        #pragma unroll
        for (int r = 0; r < 4; ++r)
          Qb[(size_t)(row0 + r) * DIM + col] = (bf16)((acc[mi][ni][r] + bi) * QSCALE);
      } else if (which == 1) {
        #pragma unroll
        for (int r = 0; r < 4; ++r)
          Kb[(size_t)(row0 + r) * DIM + col] = (bf16)(acc[mi][ni][r] + bi);
      } else {
        bf16x4 vv;
        #pragma unroll
        for (int r = 0; r < 4; ++r) vv[r] = (bf16)(acc[mi][ni][r] + bi);
        const int seq = row0 & (S_LEN - 1);
        const int t6  = seq & 63;
        const int p0  = (seq & ~63) + ((t6 >> 5) << 5) + (((t6 >> 2) & 3) << 3)
                      + (((t6 >> 4) & 1) << 2);
        *reinterpret_cast<bf16x4*>(
            &Vt[((size_t)(row0 >> 11) * DIM + col) * S_LEN + p0]) = vv;
      }
    }
  }
}

// O-projection: grid 256 (1 block/CU, single clean round), f32 out.
__global__ __launch_bounds__(256, 2)
void gemm_out(const bf16* __restrict__ A, const bf16* __restrict__ W,
              const float* __restrict__ bias, float* __restrict__ out)
{
  __shared__ __align__(16) char AB[3 * 24576];
  const int tid = threadIdx.x;
  const int L  = (blockIdx.x & 7) * 32 + (blockIdx.x >> 3);
  const int m0 = (L >> 3) * 256, n0 = (L & 7) * 128;

  G2_SETUP();
  G2_MAINLOOP();

  #pragma unroll
  for (int ni = 0; ni < 8; ++ni) {
    const int col = n0 + ni * 16 + l15;
    const float bi = bias[col];
    #pragma unroll
    for (int mi = 0; mi < 4; ++mi) {
      const int row0 = m0 + w * 64 + mi * 16 + lg * 4;
      #pragma unroll
      for (int r = 0; r < 4; ++r)
        out[(size_t)(row0 + r) * DIM + col] = acc[mi][ni][r] + bi;
    }
  }
}

// ---------------------------------------------------------------------------
// Flash attention (round-16 best, reverted from qg=4): 512 thr, qg=2,
// static-max softmax, prescaled Q, P in registers via cvt_pk + k-permuted V,
// hoisted addresses, mask via 16-entry u64 LDS LUT, dbuf K/V global_load_lds.
// ---------------------------------------------------------------------------
__global__ __launch_bounds__(512, 4)
void attn_fwd(const bf16* __restrict__ Qb, const bf16* __restrict__ Kb,
              const bf16* __restrict__ Vt, const u64* __restrict__ mbits,
              bf16* __restrict__ ctx)
{
  __shared__ __align__(16) bf16 Kbuf[2][64][64];
  __shared__ __align__(16) bf16 Vbuf[2][64][64];
  __shared__ u64 lutm[16];

  const int tid  = threadIdx.x;
  const int lane = tid & 63;
  const int l15  = lane & 15, lg = lane >> 4;
  const int L  = (blockIdx.x & 7) * 64 + (blockIdx.x >> 3);
  const int qi = L & 7;
  const int hb = L >> 3;
  const int h  = hb & 15, b = hb >> 4;
  const int w  = tid >> 6;
  const int qbase = qi * 256 + w * 32;

  if (tid < 16) {
    lutm[tid] = ((tid & 1) ? 0xFFFFull : 0) | ((tid & 2) ? 0xFFFF0000ull : 0)
              | ((tid & 4) ? 0xFFFF00000000ull : 0)
              | ((tid & 8) ? 0xFFFF000000000000ull : 0);
  }

  const int rr_s = tid >> 3;
  const int cG_s = ((tid & 7) << 4) ^ ((rr_s & 7) << 4);
  const char* gk = (const char*)Kb + ((size_t)(b * S_LEN + rr_s) * DIM + h * DK) * 2 + cG_s;
  const char* gv = (const char*)Vt + ((size_t)b * DIM + h * DK + rr_s) * (S_LEN * 2) + cG_s;
  char* lK = (char*)&Kbuf[0][0][0] + tid * 16;
  char* lV = (char*)&Vbuf[0][0][0] + tid * 16;

  const unsigned xo  = (l15 & 7) << 4;
  const unsigned ko0 = l15 * 128 + ((lg * 16) ^ xo);
  const unsigned ko1 = l15 * 128 + (((64 + lg * 16)) ^ xo);
  const char* KB = (const char*)&Kbuf[0][0][0];
  const char* VB = (const char*)&Vbuf[0][0][0];

  bf16x8 qf[2][2];
  #pragma unroll
  for (int qg = 0; qg < 2; ++qg) {
    const size_t qrow = (size_t)b * S_LEN + qbase + qg * 16 + l15;
    #pragma unroll
    for (int s = 0; s < 2; ++s)
      qf[qg][s] = *reinterpret_cast<const bf16x8*>(&Qb[qrow * DIM + h * DK + s * 32 + lg * 8]);
  }

  bf16x8 onesf;
  #pragma unroll
  for (int j = 0; j < 8; ++j) onesf[j] = (bf16)1.0f;

  union pqu { unsigned u[8]; bf16x8 frag[2]; };

  f32x4 o[2][4] = {};
  f32x4 o_l[2] = {};
  const u64* mp0 = mbits + ((size_t)b * S_LEN + qbase + l15) * (S_LEN / 64);
  const u64* mp1 = mp0 + (size_t)16 * (S_LEN / 64);

  gload16(gk, lK);  gload16(gv, lV);
  gk += 64 * DIM * 2;  gv += 64 * 2;
  u64 mbc[2] = { mp0[0], mp1[0] };
  mp0++; mp1++;

  const int NT = S_LEN / 64;   // 32
  for (int t = 0; t < NT; ++t) {
    asm volatile("s_waitcnt vmcnt(0)" ::: "memory");
    __syncthreads();

    u64 mbn[2] = {0, 0};
    if (t + 1 < NT) {
      mbn[0] = *mp0++;
      mbn[1] = *mp1++;
      const unsigned nb = ((t + 1) & 1) << 13;
      gload16(gk, lK + nb);
      gload16(gv, lV + nb);
      gk += 64 * DIM * 2;
      gv += 64 * 2;
    }

    const unsigned tb = (t & 1) << 13;

    f32x4 sc[2][4] = {};
    __builtin_amdgcn_s_setprio(1);
    #pragma unroll
    for (int s = 0; s < 2; ++s) {
      const char* kp = KB + tb + (s ? ko1 : ko0);
      #pragma unroll
      for (int nf = 0; nf < 4; ++nf) {
        bf16x8 kf = *reinterpret_cast<const bf16x8*>(kp + nf * 2048);
        sc[0][nf] = __builtin_amdgcn_mfma_f32_16x16x32_bf16(kf, qf[0][s], sc[0][nf], 0, 0, 0);
        sc[1][nf] = __builtin_amdgcn_mfma_f32_16x16x32_bf16(kf, qf[1][s], sc[1][nf], 0, 0, 0);
      }
    }
    __builtin_amdgcn_s_setprio(0);

    const u64 sh0 = mbc[0] >> (lg * 4);
    const u64 sh1 = mbc[1] >> (lg * 4);
    pqu W[2];
    #pragma unroll
    for (int qg = 0; qg < 2; ++qg) {
      const u64 sh = qg ? sh1 : sh0;
      #pragma unroll
      for (int nf = 0; nf < 4; ++nf) {
        const unsigned idx = ((unsigned)(sh >> (nf * 16))) & 15u;
        const u64 mk = lutm[idx];
        float e0 = exp2fast(sc[qg][nf][0]);
        float e1 = exp2fast(sc[qg][nf][1]);
        float e2 = exp2fast(sc[qg][nf][2]);
        float e3 = exp2fast(sc[qg][nf][3]);
        W[qg].u[nf * 2 + 0] = cvt_pk_bf16(e0, e1) & (unsigned)mk;
        W[qg].u[nf * 2 + 1] = cvt_pk_bf16(e2, e3) & (unsigned)(mk >> 32);
      }
    }

    __builtin_amdgcn_s_setprio(1);
    #pragma unroll
    for (int s = 0; s < 2; ++s) {
      const char* vp = VB + tb + (s ? ko1 : ko0);
      #pragma unroll
      for (int nf = 0; nf < 4; ++nf) {
        bf16x8 vf = *reinterpret_cast<const bf16x8*>(vp + nf * 2048);
        o[0][nf] = __builtin_amdgcn_mfma_f32_16x16x32_bf16(W[0].frag[s], vf, o[0][nf], 0, 0, 0);
        o[1][nf] = __builtin_amdgcn_mfma_f32_16x16x32_bf16(W[1].frag[s], vf, o[1][nf], 0, 0, 0);
      }
      o_l[0] = __builtin_amdgcn_mfma_f32_16x16x32_bf16(W[0].frag[s], onesf, o_l[0], 0, 0, 0);
      o_l[1] = __builtin_amdgcn_mfma_f32_16x16x32_bf16(W[1].frag[s], onesf, o_l[1], 0, 0, 0);
    }
    __builtin_amdgcn_s_setprio(0);

    mbc[0] = mbn[0]; mbc[1] = mbn[1];
  }

  #pragma unroll
  for (int qg = 0; qg < 2; ++qg) {
    float lf[4];
    #pragma unroll
    for (int r = 0; r < 4; ++r) lf[r] = 1.0f / o_l[qg][r];
    #pragma unroll
    for (int nf = 0; nf < 4; ++nf)
      #pragma unroll
      for (int r = 0; r < 4; ++r) {
        const int q = qbase + qg * 16 + lg * 4 + r;
        ctx[((size_t)b * S_LEN + q) * DIM + h * DK + nf * 16 + l15] = (bf16)(o[qg][nf][r] * lf[r]);
      }
  }
}

// ---------------------------------------------------------------------------
extern "C" void kernel_launch(void* const* d_in, const int* in_sizes, int n_in,
                              void* d_out, int out_size, void* d_ws, size_t ws_size,
                              hipStream_t stream)
{
  const float* q    = (const float*)d_in[0];
  const float* k    = (const float*)d_in[1];
  const float* v    = (const float*)d_in[2];
  const int*   mask = (const int*)  d_in[3];
  const float* Wq   = (const float*)d_in[4];
  const float* bq   = (const float*)d_in[5];
  const float* Wk   = (const float*)d_in[6];
  const float* bk   = (const float*)d_in[7];
  const float* Wv   = (const float*)d_in[8];
  const float* bv   = (const float*)d_in[9];
  const float* Wo   = (const float*)d_in[10];
  const float* bo   = (const float*)d_in[11];
  float* out = (float*)d_out;

  const size_t NE = (size_t)BATCH * S_LEN * DIM;  // 8.39M elements
  const size_t NW = (size_t)DIM * DIM;            // 1.05M elements
  bf16* qB  = (bf16*)d_ws;                        // bf16 copies of inputs
  bf16* kB  = qB + NE;
  bf16* vB  = kB + NE;
  bf16* Qb  = vB + NE;                            // projected Q,K,V
  bf16* Kb  = Qb + NE;
  bf16* Vt  = Kb + NE;
  bf16* WqB = Vt + NE;                            // bf16 weights
  bf16* WkB = WqB + NW;
  bf16* WvB = WkB + NW;
  bf16* WoB = WvB + NW;
  u64*  bits = (u64*)(WoB + NW);                  // 2 MB
  bf16* ctx = qB;                                 // reuse: qB dead after QKV GEMMs

  conv_pack<<<dim3(4096, 5), 256, 0, stream>>>(q, k, v, Wq, Wk, Wv, Wo,
                                               qB, kB, vB, WqB, WkB, WvB, WoB,
                                               mask, bits);

  gemm_qkv<<<768, 256, 0, stream>>>(qB, kB, vB, WqB, WkB, WvB,
                                    bq, bk, bv, Qb, Kb, Vt);

  attn_fwd<<<512, 512, 0, stream>>>(Qb, Kb, Vt, bits, ctx);

  gemm_out<<<256, 256, 0, stream>>>(ctx, WoB, bo, out);
}